// Round 6
// baseline (1704.235 us; speedup 1.0000x reference)
//
#include <hip/hip_runtime.h>
#include <hip/hip_bf16.h>
#include <math.h>

#define CCH 128   // C
#define DK  32    // edge feature dim
#define NCLS 10

typedef __attribute__((ext_vector_type(2))) float f32x2;

__device__ __forceinline__ float leaky_f(float v) { return v >= 0.f ? v : 0.01f * v; }

// sigmoid(gf) * softplus(gs), per component
__device__ __forceinline__ f32x2 gate2(f32x2 gf, f32x2 gs) {
  float sgx = 1.f / (1.f + __expf(-gf.x));
  float sgy = 1.f / (1.f + __expf(-gf.y));
  float spx = fmaxf(gs.x, 0.f) + __logf(1.f + __expf(-fabsf(gs.x)));
  float spy = fmaxf(gs.y, 0.f) + __logf(1.f + __expf(-fabsf(gs.y)));
  f32x2 r = {sgx * spx, sgy * spy};
  return r;
}

// ---------------- CSR build ----------------
__global__ void k_hist(const int* __restrict__ dst, int* __restrict__ cnt, int E) {
  int e = blockIdx.x * 256 + threadIdx.x;
  if (e < E) atomicAdd(&cnt[dst[e]], 1);
}

// shuffle-based scan: 3 barriers per 1024-chunk instead of ~20
__global__ void k_scan(const int* __restrict__ cnt, int* __restrict__ off,
                       int* __restrict__ cur, int N) {
  __shared__ int wsum[16];
  __shared__ int carry_s;
  int t = threadIdx.x;
  int lane = t & 63, w = t >> 6;
  if (t == 0) carry_s = 0;
  __syncthreads();
  for (int base = 0; base < N; base += 1024) {
    int i = base + t;
    int carry = carry_s;  // value from previous chunk (all threads read pre-barrier-A)
    int v = (i < N) ? cnt[i] : 0;
    int s = v;
    #pragma unroll
    for (int d = 1; d < 64; d <<= 1) {
      int tmp = __shfl_up(s, d);
      if (lane >= d) s += tmp;
    }
    if (lane == 63) wsum[w] = s;
    __syncthreads();  // A: wsum ready, carry reads done
    if (t < 16) {
      int u = wsum[t];
      #pragma unroll
      for (int d = 1; d < 16; d <<= 1) {
        int tmp = __shfl_up(u, d);
        if (t >= d) u += tmp;
      }
      wsum[t] = u;  // inclusive scan of wave sums
      if (t == 15) carry_s = carry + u;
    }
    __syncthreads();  // B: wsum scanned
    int wbase = carry + (w > 0 ? wsum[w - 1] : 0);
    int excl = wbase + s - v;
    if (i < N) { off[i] = excl; cur[i] = excl; }
    __syncthreads();  // C: protect wsum from next chunk's writes
  }
  if (t == 0) off[N] = carry_s;
}

// fill CSR, pre-gathering src node per slot (removes one dependent load in k_agg)
__global__ void k_fill(const int* __restrict__ dst, const int* __restrict__ srcArr,
                       int* __restrict__ cur, int* __restrict__ eid,
                       int* __restrict__ esrc, int E) {
  int e = blockIdx.x * 256 + threadIdx.x;
  if (e < E) {
    int p = atomicAdd(&cur[dst[e]], 1);
    eid[p] = e;
    esrc[p] = srcArr[e];
  }
}

// gather edge attrs into CSR-slot order: ea_csr[i] = ea[eid[i]].
__global__ void k_gea(const int* __restrict__ eid, const float* __restrict__ ea,
                      float* __restrict__ ea_csr, int E) {
  int t = blockIdx.x * 256 + threadIdx.x;
  if (t >= E * 8) return;
  int i = t >> 3, q = t & 7;           // slot i, float4 chunk q
  int e = eid[i];                       // 8 neighboring threads share this (L1 broadcast)
  *(float4*)&ea_csr[(size_t)i * DK + q * 4] =
      *(const float4*)&ea[(size_t)e * DK + q * 4];
}

// ---------------- initial embed: h = leaky(x @ lin_W[0:128] + lin_b + lin_W[128+cls]) ----------------
__global__ __launch_bounds__(256) void k_embed(
    const float* __restrict__ x, const float* __restrict__ lin_W,
    const float* __restrict__ lin_b, const int* __restrict__ batch,
    const int* __restrict__ y, float* __restrict__ h, int M) {
  __shared__ float Al[32 * 128];
  __shared__ float Wl[32 * 128];
  int t = threadIdx.x;
  int row0 = blockIdx.x * 32;
  for (int i = t * 4; i < 32 * 128; i += 1024) {
    int r = i >> 7, k = i & 127;
    int gr = row0 + r;
    float4 v = {0.f, 0.f, 0.f, 0.f};
    if (gr < M) v = *(const float4*)&x[(size_t)gr * 128 + k];
    *(float4*)&Al[i] = v;
  }
  int c4 = (t & 31) * 4;
  int rb = (t >> 5) * 4;
  float acc[4][4] = {};
  for (int ks = 0; ks < 128; ks += 32) {
    __syncthreads();
    for (int i = t * 4; i < 32 * 128; i += 1024)
      *(float4*)&Wl[i] = *(const float4*)&lin_W[(size_t)ks * 128 + i];
    __syncthreads();
    for (int k = 0; k < 32; k += 4) {
      float4 a[4];
      #pragma unroll
      for (int r = 0; r < 4; ++r) a[r] = *(float4*)&Al[(rb + r) * 128 + ks + k];
      #pragma unroll
      for (int kk = 0; kk < 4; ++kk) {
        float4 w = *(float4*)&Wl[(k + kk) * 128 + c4];
        #pragma unroll
        for (int r = 0; r < 4; ++r) {
          float av = kk == 0 ? a[r].x : kk == 1 ? a[r].y : kk == 2 ? a[r].z : a[r].w;
          acc[r][0] = fmaf(av, w.x, acc[r][0]);
          acc[r][1] = fmaf(av, w.y, acc[r][1]);
          acc[r][2] = fmaf(av, w.z, acc[r][2]);
          acc[r][3] = fmaf(av, w.w, acc[r][3]);
        }
      }
    }
  }
  #pragma unroll
  for (int r = 0; r < 4; ++r) {
    int gr = row0 + rb + r;
    if (gr < M) {
      int cls = y[batch[gr]];
      const float* wrow = &lin_W[(size_t)(128 + cls) * 128];
      float4 o;
      o.x = leaky_f(acc[r][0] + lin_b[c4 + 0] + wrow[c4 + 0]);
      o.y = leaky_f(acc[r][1] + lin_b[c4 + 1] + wrow[c4 + 1]);
      o.z = leaky_f(acc[r][2] + lin_b[c4 + 2] + wrow[c4 + 2]);
      o.w = leaky_f(acc[r][3] + lin_b[c4 + 3] + wrow[c4 + 3]);
      *(float4*)&h[(size_t)gr * 128 + c4] = o;
    }
  }
}

// ---------------- per-conv node projections: P[n] = [h@Wf_top | h@Wf_mid | h@Ws_top | h@Ws_mid] ----------------
__global__ __launch_bounds__(256) void k_proj(
    const float* __restrict__ h, const float* __restrict__ Wf,
    const float* __restrict__ Ws, float* __restrict__ P, int M) {
  __shared__ float Al[32 * 128];
  __shared__ float Wl[32 * 128];
  int t = threadIdx.x;
  int part = blockIdx.y;  // 0:Af 1:Bf 2:As 3:Bs
  const float* Wsrc = (part < 2 ? Wf : Ws) + (size_t)(part & 1) * (128 * 128);
  int row0 = blockIdx.x * 32;
  for (int i = t * 4; i < 32 * 128; i += 1024) {
    int r = i >> 7, k = i & 127;
    int gr = row0 + r;
    float4 v = {0.f, 0.f, 0.f, 0.f};
    if (gr < M) v = *(const float4*)&h[(size_t)gr * 128 + k];
    *(float4*)&Al[i] = v;
  }
  int c4 = (t & 31) * 4;
  int rb = (t >> 5) * 4;
  float acc[4][4] = {};
  for (int ks = 0; ks < 128; ks += 32) {
    __syncthreads();
    for (int i = t * 4; i < 32 * 128; i += 1024)
      *(float4*)&Wl[i] = *(const float4*)&Wsrc[(size_t)ks * 128 + i];
    __syncthreads();
    for (int k = 0; k < 32; k += 4) {
      float4 a[4];
      #pragma unroll
      for (int r = 0; r < 4; ++r) a[r] = *(float4*)&Al[(rb + r) * 128 + ks + k];
      #pragma unroll
      for (int kk = 0; kk < 4; ++kk) {
        float4 w = *(float4*)&Wl[(k + kk) * 128 + c4];
        #pragma unroll
        for (int r = 0; r < 4; ++r) {
          float av = kk == 0 ? a[r].x : kk == 1 ? a[r].y : kk == 2 ? a[r].z : a[r].w;
          acc[r][0] = fmaf(av, w.x, acc[r][0]);
          acc[r][1] = fmaf(av, w.y, acc[r][1]);
          acc[r][2] = fmaf(av, w.z, acc[r][2]);
          acc[r][3] = fmaf(av, w.w, acc[r][3]);
        }
      }
    }
  }
  #pragma unroll
  for (int r = 0; r < 4; ++r) {
    int gr = row0 + rb + r;
    if (gr < M) {
      float4 o = {acc[r][0], acc[r][1], acc[r][2], acc[r][3]};
      *(float4*)&P[(size_t)gr * 512 + part * 128 + c4] = o;
    }
  }
}

// ---------------- fused aggregation (pull, CSR) ----------------
// R6: stall-bound fix. VALU re-accounting (355 busy-cy/edge measured == 355
// legit with pk_fma at half-rate) shows NO junk instructions — the other 48%
// of wall time is stalls: per-edge wf/ws re-fetch from L1 (compiler never
// register-allocates the 128-reg weight set; 3 attempts, 3 no-ops) and/or
// unoverlapped L3 latency on the two P[src] gathers.
// Fix for both without fighting the allocator: 4 edges per iteration.
//  - weights loaded once per k-chunk, applied to 4 edges (L1 traffic /4)
//  - 8 independent P gathers issued up-front, hidden under 4 edges of FMA
__global__ __launch_bounds__(256)
void k_agg(
    const float* __restrict__ hin, const float* __restrict__ P,
    const int* __restrict__ off,
    const int* __restrict__ esrcArr, const float* __restrict__ ea_csr,
    const float* __restrict__ Wf, const float* __restrict__ Ws,
    const float* __restrict__ bfv, const float* __restrict__ bsv,
    float* __restrict__ hout, int N, int do_leaky) {
  int lane = threadIdx.x & 63;
  int wave = __builtin_amdgcn_readfirstlane(threadIdx.x >> 6);
  int gw = blockIdx.x * 4 + wave;
  int c2 = lane * 2;  // this lane owns channels c2, c2+1
  const float* wfp = Wf + (size_t)256 * 128 + c2;  // wfp[k*128] = wf[k] pair
  const float* wsp = Ws + (size_t)256 * 128 + c2;
  f32x2 bf2 = *(const f32x2*)&bfv[c2];
  f32x2 bs2 = *(const f32x2*)&bsv[c2];
  int nstreams = gridDim.x * 4;
  for (int n = gw; n < N; n += nstreams) {
    int i0 = __builtin_amdgcn_readfirstlane(off[n]);
    int i1 = __builtin_amdgcn_readfirstlane(off[n + 1]);
    f32x2 acc = *(const f32x2*)&hin[(size_t)n * 128 + c2];
    f32x2 gf0 = *(const f32x2*)&P[(size_t)n * 512 + c2] + bf2;        // Af + bf
    f32x2 gs0 = *(const f32x2*)&P[(size_t)n * 512 + 256 + c2] + bs2;  // As + bs
    int i = i0;
    // ---- 4-edge groups ----
    for (; i + 4 <= i1; i += 4) {
      int s0 = __builtin_amdgcn_readfirstlane(esrcArr[i + 0]);
      int s1 = __builtin_amdgcn_readfirstlane(esrcArr[i + 1]);
      int s2 = __builtin_amdgcn_readfirstlane(esrcArr[i + 2]);
      int s3 = __builtin_amdgcn_readfirstlane(esrcArr[i + 3]);
      // issue all 8 gathers up-front (independent; hidden under FMA below)
      f32x2 gfa = gf0 + *(const f32x2*)&P[(size_t)s0 * 512 + 128 + c2];
      f32x2 gfb = gf0 + *(const f32x2*)&P[(size_t)s1 * 512 + 128 + c2];
      f32x2 gfc = gf0 + *(const f32x2*)&P[(size_t)s2 * 512 + 128 + c2];
      f32x2 gfd = gf0 + *(const f32x2*)&P[(size_t)s3 * 512 + 128 + c2];
      f32x2 gsa = gs0 + *(const f32x2*)&P[(size_t)s0 * 512 + 384 + c2];
      f32x2 gsb = gs0 + *(const f32x2*)&P[(size_t)s1 * 512 + 384 + c2];
      f32x2 gsc = gs0 + *(const f32x2*)&P[(size_t)s2 * 512 + 384 + c2];
      f32x2 gsd = gs0 + *(const f32x2*)&P[(size_t)s3 * 512 + 384 + c2];
      const float* e0 = ea_csr + (size_t)i * DK;
      #pragma unroll
      for (int q = 0; q < 8; ++q) {
        float4 ev0 = *(const float4*)&e0[q * 4];
        float4 ev1 = *(const float4*)&e0[DK + q * 4];
        float4 ev2 = *(const float4*)&e0[2 * DK + q * 4];
        float4 ev3 = *(const float4*)&e0[3 * DK + q * 4];
        #pragma unroll
        for (int j = 0; j < 4; ++j) {
          int k = q * 4 + j;
          f32x2 wfk = *(const f32x2*)&wfp[(size_t)k * 128];  // shared by 4 edges
          f32x2 wsk = *(const f32x2*)&wsp[(size_t)k * 128];
          float a = j == 0 ? ev0.x : j == 1 ? ev0.y : j == 2 ? ev0.z : ev0.w;
          float b = j == 0 ? ev1.x : j == 1 ? ev1.y : j == 2 ? ev1.z : ev1.w;
          float c = j == 0 ? ev2.x : j == 1 ? ev2.y : j == 2 ? ev2.z : ev2.w;
          float d = j == 0 ? ev3.x : j == 1 ? ev3.y : j == 2 ? ev3.z : ev3.w;
          f32x2 a2 = {a, a}, b2 = {b, b}, c2v = {c, c}, d2 = {d, d};
          gfa += a2 * wfk; gsa += a2 * wsk;
          gfb += b2 * wfk; gsb += b2 * wsk;
          gfc += c2v * wfk; gsc += c2v * wsk;
          gfd += d2 * wfk; gsd += d2 * wsk;
        }
      }
      acc += gate2(gfa, gsa);
      acc += gate2(gfb, gsb);
      acc += gate2(gfc, gsc);
      acc += gate2(gfd, gsd);
    }
    // ---- tail ----
    for (; i < i1; ++i) {
      int s = __builtin_amdgcn_readfirstlane(esrcArr[i]);
      f32x2 gf = gf0 + *(const f32x2*)&P[(size_t)s * 512 + 128 + c2];
      f32x2 gs = gs0 + *(const f32x2*)&P[(size_t)s * 512 + 384 + c2];
      const float* e0 = ea_csr + (size_t)i * DK;
      #pragma unroll
      for (int q = 0; q < 8; ++q) {
        float4 ev = *(const float4*)&e0[q * 4];
        #pragma unroll
        for (int j = 0; j < 4; ++j) {
          int k = q * 4 + j;
          f32x2 wfk = *(const f32x2*)&wfp[(size_t)k * 128];
          f32x2 wsk = *(const f32x2*)&wsp[(size_t)k * 128];
          float e = j == 0 ? ev.x : j == 1 ? ev.y : j == 2 ? ev.z : ev.w;
          f32x2 e2 = {e, e};
          gf += e2 * wfk;
          gs += e2 * wsk;
        }
      }
      acc += gate2(gf, gs);
    }
    if (do_leaky) { acc.x = leaky_f(acc.x); acc.y = leaky_f(acc.y); }
    *(f32x2*)&hout[(size_t)n * 128 + c2] = acc;
  }
}

// ---------------- per-graph mean pool: partial sums over (G, S) grid ----------------
__device__ __forceinline__ int lbound(const int* a, int n, int key) {
  int lo = 0, hi = n;
  while (lo < hi) { int m = (lo + hi) >> 1; if (a[m] < key) lo = m + 1; else hi = m; }
  return lo;
}

__global__ void k_pool(const float* __restrict__ h, const int* __restrict__ batch,
                       float* __restrict__ pooled, int* __restrict__ gcnt, int N) {
  int g = blockIdx.x;
  int sidx = blockIdx.y, sgrid = gridDim.y;
  int t = threadIdx.x;  // 128 threads = channels
  int lo = lbound(batch, N, g);
  int hi = lbound(batch, N, g + 1);
  int len = hi - lo;
  if (sidx == 0 && t == 0) gcnt[g] = len;
  int per = (len + sgrid - 1) / sgrid;
  int a = lo + sidx * per;
  int b = min(hi, a + per);
  if (a >= b) return;
  float s = 0.f;
  for (int n = a; n < b; ++n) s += h[(size_t)n * 128 + t];
  atomicAdd(&pooled[g * 128 + t], s);
}

// ---------------- head: one-hot folded in as fc1_W row (128 + y[g]) ----------------
__global__ void k_fc(const float* __restrict__ pooled, const int* __restrict__ gcnt,
                     const int* __restrict__ y,
                     const float* __restrict__ W1, const float* __restrict__ b1,
                     const float* __restrict__ W2, const float* __restrict__ b2,
                     float* __restrict__ out) {
  int g = blockIdx.x;
  int j = threadIdx.x;  // 64 threads, only 0..31 compute
  float v = 0.f;
  if (j < 32) {
    int cnt = gcnt[g];
    float dot = 0.f;
    for (int k = 0; k < 128; ++k) dot = fmaf(pooled[g * 128 + k], W1[k * 32 + j], dot);
    float a = b1[j] + (cnt > 0 ? dot / (float)cnt + W1[(128 + y[g]) * 32 + j] : 0.f);
    a = leaky_f(a);
    v = a * W2[j];
  }
  #pragma unroll
  for (int o = 32; o > 0; o >>= 1) v += __shfl_down(v, o);
  if (j == 0) out[g] = 1.f / (1.f + __expf(-(v + b2[0])));
}

extern "C" void kernel_launch(void* const* d_in, const int* in_sizes, int n_in,
                              void* d_out, int out_size, void* d_ws, size_t ws_size,
                              hipStream_t stream) {
  const float* x        = (const float*)d_in[0];
  const int*   y        = (const int*)d_in[1];
  const int*   eidx     = (const int*)d_in[2];
  const float* ea       = (const float*)d_in[3];
  const int*   batch    = (const int*)d_in[4];
  const float* lin_W    = (const float*)d_in[5];
  const float* lin_b    = (const float*)d_in[6];
  const float* c1_Wf    = (const float*)d_in[7];
  const float* c1_bf    = (const float*)d_in[8];
  const float* c1_Ws    = (const float*)d_in[9];
  const float* c1_bs    = (const float*)d_in[10];
  const float* c2_Wf    = (const float*)d_in[11];
  const float* c2_bf    = (const float*)d_in[12];
  const float* c2_Ws    = (const float*)d_in[13];
  const float* c2_bs    = (const float*)d_in[14];
  const float* fc1_W    = (const float*)d_in[15];
  const float* fc1_b    = (const float*)d_in[16];
  const float* fc2_W    = (const float*)d_in[17];
  const float* fc2_b    = (const float*)d_in[18];
  float* out = (float*)d_out;

  const int N = in_sizes[0] / 128;
  const int G = in_sizes[1];
  const int E = in_sizes[2] / 2;
  const int* src = eidx;
  const int* dst = eidx + E;

  // workspace layout (16B aligned chunks)
  char* w = (char*)d_ws;
  float* P  = (float*)w;  w += (size_t)N * 512 * 4;
  float* hA = (float*)w;  w += (size_t)N * 128 * 4;
  float* hB = (float*)w;  w += (size_t)N * 128 * 4;
  float* pooled = (float*)w; w += (size_t)G * 128 * 4;
  int* gcnt = (int*)w; w += ((size_t)G * 4 + 15) & ~(size_t)15;
  int* cnt = (int*)w; w += (size_t)N * 4;
  int* off = (int*)w; w += ((size_t)(N + 1) * 4 + 15) & ~(size_t)15;
  int* eid = (int*)w; w += (size_t)E * 4;
  int* esrc = (int*)w; w += (size_t)E * 4;
  float* ea_csr = (float*)w; w += (size_t)E * DK * 4;

  // CSR build
  hipMemsetAsync(cnt, 0, (size_t)N * 4, stream);
  hipMemsetAsync(pooled, 0, (size_t)G * 128 * 4, stream);
  k_hist<<<(E + 255) / 256, 256, 0, stream>>>(dst, cnt, E);
  k_scan<<<1, 1024, 0, stream>>>(cnt, off, cnt /*reuse as cursor*/, N);
  k_fill<<<(E + 255) / 256, 256, 0, stream>>>(dst, src, cnt, eid, esrc, E);
  k_gea<<<(E * 8 + 255) / 256, 256, 0, stream>>>(eid, ea, ea_csr, E);

  // embed
  k_embed<<<(N + 31) / 32, 256, 0, stream>>>(x, lin_W, lin_b, batch, y, hA, N);

  // conv1
  k_proj<<<dim3((N + 31) / 32, 4), 256, 0, stream>>>(hA, c1_Wf, c1_Ws, P, N);
  k_agg<<<2048, 256, 0, stream>>>(hA, P, off, esrc, ea_csr, c1_Wf, c1_Ws, c1_bf, c1_bs, hB, N, 1);

  // conv2
  k_proj<<<dim3((N + 31) / 32, 4), 256, 0, stream>>>(hB, c2_Wf, c2_Ws, P, N);
  k_agg<<<2048, 256, 0, stream>>>(hB, P, off, esrc, ea_csr, c2_Wf, c2_Ws, c2_bf, c2_bs, hA, N, 0);

  // pool + head
  k_pool<<<dim3(G, 8), 128, 0, stream>>>(hA, batch, pooled, gcnt, N);
  k_fc<<<G, 64, 0, stream>>>(pooled, gcnt, y, fc1_W, fc1_b, fc2_W, fc2_b, out);
}

// Round 7
// 1239.505 us; speedup vs baseline: 1.3749x; 1.3749x over previous
//
#include <hip/hip_runtime.h>
#include <hip/hip_bf16.h>
#include <math.h>

#define CCH 128   // C
#define DK  32    // edge feature dim
#define NCLS 10

typedef __attribute__((ext_vector_type(2))) float f32x2;

__device__ __forceinline__ float leaky_f(float v) { return v >= 0.f ? v : 0.01f * v; }

// sigmoid(gf) * softplus(gs), per component
__device__ __forceinline__ f32x2 gate2(f32x2 gf, f32x2 gs) {
  float sgx = 1.f / (1.f + __expf(-gf.x));
  float sgy = 1.f / (1.f + __expf(-gf.y));
  float spx = fmaxf(gs.x, 0.f) + __logf(1.f + __expf(-fabsf(gs.x)));
  float spy = fmaxf(gs.y, 0.f) + __logf(1.f + __expf(-fabsf(gs.y)));
  f32x2 r = {sgx * spx, sgy * spy};
  return r;
}

// ---------------- CSR build ----------------
__global__ void k_hist(const int* __restrict__ dst, int* __restrict__ cnt, int E) {
  int e = blockIdx.x * 256 + threadIdx.x;
  if (e < E) atomicAdd(&cnt[dst[e]], 1);
}

// shuffle-based scan: 3 barriers per 1024-chunk instead of ~20
__global__ void k_scan(const int* __restrict__ cnt, int* __restrict__ off,
                       int* __restrict__ cur, int N) {
  __shared__ int wsum[16];
  __shared__ int carry_s;
  int t = threadIdx.x;
  int lane = t & 63, w = t >> 6;
  if (t == 0) carry_s = 0;
  __syncthreads();
  for (int base = 0; base < N; base += 1024) {
    int i = base + t;
    int carry = carry_s;  // value from previous chunk (all threads read pre-barrier-A)
    int v = (i < N) ? cnt[i] : 0;
    int s = v;
    #pragma unroll
    for (int d = 1; d < 64; d <<= 1) {
      int tmp = __shfl_up(s, d);
      if (lane >= d) s += tmp;
    }
    if (lane == 63) wsum[w] = s;
    __syncthreads();  // A: wsum ready, carry reads done
    if (t < 16) {
      int u = wsum[t];
      #pragma unroll
      for (int d = 1; d < 16; d <<= 1) {
        int tmp = __shfl_up(u, d);
        if (t >= d) u += tmp;
      }
      wsum[t] = u;  // inclusive scan of wave sums
      if (t == 15) carry_s = carry + u;
    }
    __syncthreads();  // B: wsum scanned
    int wbase = carry + (w > 0 ? wsum[w - 1] : 0);
    int excl = wbase + s - v;
    if (i < N) { off[i] = excl; cur[i] = excl; }
    __syncthreads();  // C: protect wsum from next chunk's writes
  }
  if (t == 0) off[N] = carry_s;
}

// fill CSR, pre-gathering src node per slot (removes one dependent load in k_agg)
__global__ void k_fill(const int* __restrict__ dst, const int* __restrict__ srcArr,
                       int* __restrict__ cur, int* __restrict__ eid,
                       int* __restrict__ esrc, int E) {
  int e = blockIdx.x * 256 + threadIdx.x;
  if (e < E) {
    int p = atomicAdd(&cur[dst[e]], 1);
    eid[p] = e;
    esrc[p] = srcArr[e];
  }
}

// gather edge attrs into CSR-slot order: ea_csr[i] = ea[eid[i]].
__global__ void k_gea(const int* __restrict__ eid, const float* __restrict__ ea,
                      float* __restrict__ ea_csr, int E) {
  int t = blockIdx.x * 256 + threadIdx.x;
  if (t >= E * 8) return;
  int i = t >> 3, q = t & 7;           // slot i, float4 chunk q
  int e = eid[i];                       // 8 neighboring threads share this (L1 broadcast)
  *(float4*)&ea_csr[(size_t)i * DK + q * 4] =
      *(const float4*)&ea[(size_t)e * DK + q * 4];
}

// ---------------- initial embed: h = leaky(x @ lin_W[0:128] + lin_b + lin_W[128+cls]) ----------------
__global__ __launch_bounds__(256) void k_embed(
    const float* __restrict__ x, const float* __restrict__ lin_W,
    const float* __restrict__ lin_b, const int* __restrict__ batch,
    const int* __restrict__ y, float* __restrict__ h, int M) {
  __shared__ float Al[32 * 128];
  __shared__ float Wl[32 * 128];
  int t = threadIdx.x;
  int row0 = blockIdx.x * 32;
  for (int i = t * 4; i < 32 * 128; i += 1024) {
    int r = i >> 7, k = i & 127;
    int gr = row0 + r;
    float4 v = {0.f, 0.f, 0.f, 0.f};
    if (gr < M) v = *(const float4*)&x[(size_t)gr * 128 + k];
    *(float4*)&Al[i] = v;
  }
  int c4 = (t & 31) * 4;
  int rb = (t >> 5) * 4;
  float acc[4][4] = {};
  for (int ks = 0; ks < 128; ks += 32) {
    __syncthreads();
    for (int i = t * 4; i < 32 * 128; i += 1024)
      *(float4*)&Wl[i] = *(const float4*)&lin_W[(size_t)ks * 128 + i];
    __syncthreads();
    for (int k = 0; k < 32; k += 4) {
      float4 a[4];
      #pragma unroll
      for (int r = 0; r < 4; ++r) a[r] = *(float4*)&Al[(rb + r) * 128 + ks + k];
      #pragma unroll
      for (int kk = 0; kk < 4; ++kk) {
        float4 w = *(float4*)&Wl[(k + kk) * 128 + c4];
        #pragma unroll
        for (int r = 0; r < 4; ++r) {
          float av = kk == 0 ? a[r].x : kk == 1 ? a[r].y : kk == 2 ? a[r].z : a[r].w;
          acc[r][0] = fmaf(av, w.x, acc[r][0]);
          acc[r][1] = fmaf(av, w.y, acc[r][1]);
          acc[r][2] = fmaf(av, w.z, acc[r][2]);
          acc[r][3] = fmaf(av, w.w, acc[r][3]);
        }
      }
    }
  }
  #pragma unroll
  for (int r = 0; r < 4; ++r) {
    int gr = row0 + rb + r;
    if (gr < M) {
      int cls = y[batch[gr]];
      const float* wrow = &lin_W[(size_t)(128 + cls) * 128];
      float4 o;
      o.x = leaky_f(acc[r][0] + lin_b[c4 + 0] + wrow[c4 + 0]);
      o.y = leaky_f(acc[r][1] + lin_b[c4 + 1] + wrow[c4 + 1]);
      o.z = leaky_f(acc[r][2] + lin_b[c4 + 2] + wrow[c4 + 2]);
      o.w = leaky_f(acc[r][3] + lin_b[c4 + 3] + wrow[c4 + 3]);
      *(float4*)&h[(size_t)gr * 128 + c4] = o;
    }
  }
}

// ---------------- per-conv node projections: P[n] = [h@Wf_top | h@Wf_mid | h@Ws_top | h@Ws_mid] ----------------
__global__ __launch_bounds__(256) void k_proj(
    const float* __restrict__ h, const float* __restrict__ Wf,
    const float* __restrict__ Ws, float* __restrict__ P, int M) {
  __shared__ float Al[32 * 128];
  __shared__ float Wl[32 * 128];
  int t = threadIdx.x;
  int part = blockIdx.y;  // 0:Af 1:Bf 2:As 3:Bs
  const float* Wsrc = (part < 2 ? Wf : Ws) + (size_t)(part & 1) * (128 * 128);
  int row0 = blockIdx.x * 32;
  for (int i = t * 4; i < 32 * 128; i += 1024) {
    int r = i >> 7, k = i & 127;
    int gr = row0 + r;
    float4 v = {0.f, 0.f, 0.f, 0.f};
    if (gr < M) v = *(const float4*)&h[(size_t)gr * 128 + k];
    *(float4*)&Al[i] = v;
  }
  int c4 = (t & 31) * 4;
  int rb = (t >> 5) * 4;
  float acc[4][4] = {};
  for (int ks = 0; ks < 128; ks += 32) {
    __syncthreads();
    for (int i = t * 4; i < 32 * 128; i += 1024)
      *(float4*)&Wl[i] = *(const float4*)&Wsrc[(size_t)ks * 128 + i];
    __syncthreads();
    for (int k = 0; k < 32; k += 4) {
      float4 a[4];
      #pragma unroll
      for (int r = 0; r < 4; ++r) a[r] = *(float4*)&Al[(rb + r) * 128 + ks + k];
      #pragma unroll
      for (int kk = 0; kk < 4; ++kk) {
        float4 w = *(float4*)&Wl[(k + kk) * 128 + c4];
        #pragma unroll
        for (int r = 0; r < 4; ++r) {
          float av = kk == 0 ? a[r].x : kk == 1 ? a[r].y : kk == 2 ? a[r].z : a[r].w;
          acc[r][0] = fmaf(av, w.x, acc[r][0]);
          acc[r][1] = fmaf(av, w.y, acc[r][1]);
          acc[r][2] = fmaf(av, w.z, acc[r][2]);
          acc[r][3] = fmaf(av, w.w, acc[r][3]);
        }
      }
    }
  }
  #pragma unroll
  for (int r = 0; r < 4; ++r) {
    int gr = row0 + rb + r;
    if (gr < M) {
      float4 o = {acc[r][0], acc[r][1], acc[r][2], acc[r][3]};
      *(float4*)&P[(size_t)gr * 512 + part * 128 + c4] = o;
    }
  }
}

// ---------------- fused aggregation (pull, CSR) ----------------
// R7: occupancy fix. The R1-R6 mystery resolved: gfx950's unified VGPR/AGPR
// file — the compiler kept wf/ws in ~128 AGPRs (invisible in VGPR_Count=84),
// so each wave held ~212 regs -> 2 waves/SIMD -> 26% occupancy -> ~1000 cy of
// per-edge gather latency exposed (48% stall). VALU-busy cycles were constant
// ~190 us across R4/R5/R6, confirming the work itself was already minimal.
// Fix: weights move to LDS (32 KB, shared by all 16 waves of the block,
// conflict-free b64 reads at 2 lanes/bank), freeing each wave to ~45 VGPRs.
// launch_bounds(256,8) caps VGPR at 64; LDS then limits occupancy at
// 5 blocks/CU = 20 waves/CU = 62% — 2.4x the resident waves to hide latency.
__global__ __launch_bounds__(256, 8)
void k_agg(
    const float* __restrict__ hin, const float* __restrict__ P,
    const int* __restrict__ off,
    const int* __restrict__ esrcArr, const float* __restrict__ ea_csr,
    const float* __restrict__ Wf, const float* __restrict__ Ws,
    const float* __restrict__ bfv, const float* __restrict__ bsv,
    float* __restrict__ hout, int N, int do_leaky) {
  __shared__ float WlF[32 * 128];
  __shared__ float WlS[32 * 128];
  int t = threadIdx.x;
  // stage edge-part weight rows (256..287) into LDS, coalesced float4
  for (int i = t * 4; i < 32 * 128; i += 1024) {
    *(float4*)&WlF[i] = *(const float4*)&Wf[(size_t)256 * 128 + i];
    *(float4*)&WlS[i] = *(const float4*)&Ws[(size_t)256 * 128 + i];
  }
  __syncthreads();
  int lane = t & 63;
  int wave = __builtin_amdgcn_readfirstlane(t >> 6);
  int gw = blockIdx.x * 4 + wave;
  int c2 = lane * 2;  // this lane owns channels c2, c2+1
  f32x2 bf2 = *(const f32x2*)&bfv[c2];
  f32x2 bs2 = *(const f32x2*)&bsv[c2];
  int nstreams = gridDim.x * 4;
  for (int n = gw; n < N; n += nstreams) {
    int i0 = __builtin_amdgcn_readfirstlane(off[n]);
    int i1 = __builtin_amdgcn_readfirstlane(off[n + 1]);
    f32x2 acc = *(const f32x2*)&hin[(size_t)n * 128 + c2];
    f32x2 gf0 = *(const f32x2*)&P[(size_t)n * 512 + c2] + bf2;        // Af + bf
    f32x2 gs0 = *(const f32x2*)&P[(size_t)n * 512 + 256 + c2] + bs2;  // As + bs
    #pragma unroll 1
    for (int i = i0; i < i1; ++i) {
      int s = __builtin_amdgcn_readfirstlane(esrcArr[i]);
      f32x2 gf = gf0 + *(const f32x2*)&P[(size_t)s * 512 + 128 + c2];  // + Bf[src]
      f32x2 gs = gs0 + *(const f32x2*)&P[(size_t)s * 512 + 384 + c2];  // + Bs[src]
      const float* e0 = ea_csr + (size_t)i * DK;
      #pragma unroll
      for (int q = 0; q < 4; ++q) {
        float4 a = *(const float4*)&e0[q * 8];
        float4 b = *(const float4*)&e0[q * 8 + 4];
        float ekk[8] = {a.x, a.y, a.z, a.w, b.x, b.y, b.z, b.w};
        #pragma unroll
        for (int j = 0; j < 8; ++j) {
          int k = q * 8 + j;
          f32x2 wfk = *(const f32x2*)&WlF[k * 128 + c2];  // LDS, shared by block
          f32x2 wsk = *(const f32x2*)&WlS[k * 128 + c2];
          f32x2 e2 = {ekk[j], ekk[j]};
          gf += e2 * wfk;
          gs += e2 * wsk;
        }
      }
      acc += gate2(gf, gs);
    }
    if (do_leaky) { acc.x = leaky_f(acc.x); acc.y = leaky_f(acc.y); }
    *(f32x2*)&hout[(size_t)n * 128 + c2] = acc;
  }
}

// ---------------- per-graph mean pool: partial sums over (G, S) grid ----------------
__device__ __forceinline__ int lbound(const int* a, int n, int key) {
  int lo = 0, hi = n;
  while (lo < hi) { int m = (lo + hi) >> 1; if (a[m] < key) lo = m + 1; else hi = m; }
  return lo;
}

__global__ void k_pool(const float* __restrict__ h, const int* __restrict__ batch,
                       float* __restrict__ pooled, int* __restrict__ gcnt, int N) {
  int g = blockIdx.x;
  int sidx = blockIdx.y, sgrid = gridDim.y;
  int t = threadIdx.x;  // 128 threads = channels
  int lo = lbound(batch, N, g);
  int hi = lbound(batch, N, g + 1);
  int len = hi - lo;
  if (sidx == 0 && t == 0) gcnt[g] = len;
  int per = (len + sgrid - 1) / sgrid;
  int a = lo + sidx * per;
  int b = min(hi, a + per);
  if (a >= b) return;
  float s = 0.f;
  for (int n = a; n < b; ++n) s += h[(size_t)n * 128 + t];
  atomicAdd(&pooled[g * 128 + t], s);
}

// ---------------- head: one-hot folded in as fc1_W row (128 + y[g]) ----------------
__global__ void k_fc(const float* __restrict__ pooled, const int* __restrict__ gcnt,
                     const int* __restrict__ y,
                     const float* __restrict__ W1, const float* __restrict__ b1,
                     const float* __restrict__ W2, const float* __restrict__ b2,
                     float* __restrict__ out) {
  int g = blockIdx.x;
  int j = threadIdx.x;  // 64 threads, only 0..31 compute
  float v = 0.f;
  if (j < 32) {
    int cnt = gcnt[g];
    float dot = 0.f;
    for (int k = 0; k < 128; ++k) dot = fmaf(pooled[g * 128 + k], W1[k * 32 + j], dot);
    float a = b1[j] + (cnt > 0 ? dot / (float)cnt + W1[(128 + y[g]) * 32 + j] : 0.f);
    a = leaky_f(a);
    v = a * W2[j];
  }
  #pragma unroll
  for (int o = 32; o > 0; o >>= 1) v += __shfl_down(v, o);
  if (j == 0) out[g] = 1.f / (1.f + __expf(-(v + b2[0])));
}

extern "C" void kernel_launch(void* const* d_in, const int* in_sizes, int n_in,
                              void* d_out, int out_size, void* d_ws, size_t ws_size,
                              hipStream_t stream) {
  const float* x        = (const float*)d_in[0];
  const int*   y        = (const int*)d_in[1];
  const int*   eidx     = (const int*)d_in[2];
  const float* ea       = (const float*)d_in[3];
  const int*   batch    = (const int*)d_in[4];
  const float* lin_W    = (const float*)d_in[5];
  const float* lin_b    = (const float*)d_in[6];
  const float* c1_Wf    = (const float*)d_in[7];
  const float* c1_bf    = (const float*)d_in[8];
  const float* c1_Ws    = (const float*)d_in[9];
  const float* c1_bs    = (const float*)d_in[10];
  const float* c2_Wf    = (const float*)d_in[11];
  const float* c2_bf    = (const float*)d_in[12];
  const float* c2_Ws    = (const float*)d_in[13];
  const float* c2_bs    = (const float*)d_in[14];
  const float* fc1_W    = (const float*)d_in[15];
  const float* fc1_b    = (const float*)d_in[16];
  const float* fc2_W    = (const float*)d_in[17];
  const float* fc2_b    = (const float*)d_in[18];
  float* out = (float*)d_out;

  const int N = in_sizes[0] / 128;
  const int G = in_sizes[1];
  const int E = in_sizes[2] / 2;
  const int* src = eidx;
  const int* dst = eidx + E;

  // workspace layout (16B aligned chunks)
  char* w = (char*)d_ws;
  float* P  = (float*)w;  w += (size_t)N * 512 * 4;
  float* hA = (float*)w;  w += (size_t)N * 128 * 4;
  float* hB = (float*)w;  w += (size_t)N * 128 * 4;
  float* pooled = (float*)w; w += (size_t)G * 128 * 4;
  int* gcnt = (int*)w; w += ((size_t)G * 4 + 15) & ~(size_t)15;
  int* cnt = (int*)w; w += (size_t)N * 4;
  int* off = (int*)w; w += ((size_t)(N + 1) * 4 + 15) & ~(size_t)15;
  int* eid = (int*)w; w += (size_t)E * 4;
  int* esrc = (int*)w; w += (size_t)E * 4;
  float* ea_csr = (float*)w; w += (size_t)E * DK * 4;

  // CSR build
  hipMemsetAsync(cnt, 0, (size_t)N * 4, stream);
  hipMemsetAsync(pooled, 0, (size_t)G * 128 * 4, stream);
  k_hist<<<(E + 255) / 256, 256, 0, stream>>>(dst, cnt, E);
  k_scan<<<1, 1024, 0, stream>>>(cnt, off, cnt /*reuse as cursor*/, N);
  k_fill<<<(E + 255) / 256, 256, 0, stream>>>(dst, src, cnt, eid, esrc, E);
  k_gea<<<(E * 8 + 255) / 256, 256, 0, stream>>>(eid, ea, ea_csr, E);

  // embed
  k_embed<<<(N + 31) / 32, 256, 0, stream>>>(x, lin_W, lin_b, batch, y, hA, N);

  // conv1
  k_proj<<<dim3((N + 31) / 32, 4), 256, 0, stream>>>(hA, c1_Wf, c1_Ws, P, N);
  k_agg<<<2048, 256, 0, stream>>>(hA, P, off, esrc, ea_csr, c1_Wf, c1_Ws, c1_bf, c1_bs, hB, N, 1);

  // conv2
  k_proj<<<dim3((N + 31) / 32, 4), 256, 0, stream>>>(hB, c2_Wf, c2_Ws, P, N);
  k_agg<<<2048, 256, 0, stream>>>(hB, P, off, esrc, ea_csr, c2_Wf, c2_Ws, c2_bf, c2_bs, hA, N, 0);

  // pool + head
  k_pool<<<dim3(G, 8), 128, 0, stream>>>(hA, batch, pooled, gcnt, N);
  k_fc<<<G, 64, 0, stream>>>(pooled, gcnt, y, fc1_W, fc1_b, fc2_W, fc2_b, out);
}

// Round 8
// 1236.643 us; speedup vs baseline: 1.3781x; 1.0023x over previous
//
#include <hip/hip_runtime.h>
#include <hip/hip_bf16.h>
#include <math.h>

#define CCH 128   // C
#define DK  32    // edge feature dim
#define NCLS 10

typedef __attribute__((ext_vector_type(2))) float f32x2;
typedef __attribute__((ext_vector_type(4))) float f32x4;

__device__ __forceinline__ float leaky_f(float v) { return v >= 0.f ? v : 0.01f * v; }

// sigmoid(gf) * softplus(gs), per component
__device__ __forceinline__ f32x2 gate2(f32x2 gf, f32x2 gs) {
  float sgx = 1.f / (1.f + __expf(-gf.x));
  float sgy = 1.f / (1.f + __expf(-gf.y));
  float spx = fmaxf(gs.x, 0.f) + __logf(1.f + __expf(-fabsf(gs.x)));
  float spy = fmaxf(gs.y, 0.f) + __logf(1.f + __expf(-fabsf(gs.y)));
  f32x2 r = {sgx * spx, sgy * spy};
  return r;
}

// ---------------- CSR build ----------------
__global__ void k_hist(const int* __restrict__ dst, int* __restrict__ cnt, int E) {
  int e = blockIdx.x * 256 + threadIdx.x;
  if (e < E) atomicAdd(&cnt[dst[e]], 1);
}

// shuffle-based scan: 3 barriers per 1024-chunk instead of ~20
__global__ void k_scan(const int* __restrict__ cnt, int* __restrict__ off,
                       int* __restrict__ cur, int N) {
  __shared__ int wsum[16];
  __shared__ int carry_s;
  int t = threadIdx.x;
  int lane = t & 63, w = t >> 6;
  if (t == 0) carry_s = 0;
  __syncthreads();
  for (int base = 0; base < N; base += 1024) {
    int i = base + t;
    int carry = carry_s;  // value from previous chunk (all threads read pre-barrier-A)
    int v = (i < N) ? cnt[i] : 0;
    int s = v;
    #pragma unroll
    for (int d = 1; d < 64; d <<= 1) {
      int tmp = __shfl_up(s, d);
      if (lane >= d) s += tmp;
    }
    if (lane == 63) wsum[w] = s;
    __syncthreads();  // A: wsum ready, carry reads done
    if (t < 16) {
      int u = wsum[t];
      #pragma unroll
      for (int d = 1; d < 16; d <<= 1) {
        int tmp = __shfl_up(u, d);
        if (t >= d) u += tmp;
      }
      wsum[t] = u;  // inclusive scan of wave sums
      if (t == 15) carry_s = carry + u;
    }
    __syncthreads();  // B: wsum scanned
    int wbase = carry + (w > 0 ? wsum[w - 1] : 0);
    int excl = wbase + s - v;
    if (i < N) { off[i] = excl; cur[i] = excl; }
    __syncthreads();  // C: protect wsum from next chunk's writes
  }
  if (t == 0) off[N] = carry_s;
}

// fill CSR, pre-gathering src node per slot (removes one dependent load in k_agg)
__global__ void k_fill(const int* __restrict__ dst, const int* __restrict__ srcArr,
                       int* __restrict__ cur, int* __restrict__ eid,
                       int* __restrict__ esrc, int E) {
  int e = blockIdx.x * 256 + threadIdx.x;
  if (e < E) {
    int p = atomicAdd(&cur[dst[e]], 1);
    eid[p] = e;
    esrc[p] = srcArr[e];
  }
}

// gather edge attrs into CSR-slot order: ea_csr[i] = ea[eid[i]].
__global__ void k_gea(const int* __restrict__ eid, const float* __restrict__ ea,
                      float* __restrict__ ea_csr, int E) {
  int t = blockIdx.x * 256 + threadIdx.x;
  if (t >= E * 8) return;
  int i = t >> 3, q = t & 7;           // slot i, float4 chunk q
  int e = eid[i];                       // 8 neighboring threads share this (L1 broadcast)
  *(float4*)&ea_csr[(size_t)i * DK + q * 4] =
      *(const float4*)&ea[(size_t)e * DK + q * 4];
}

// ---------------- initial embed: h = leaky(x @ lin_W[0:128] + lin_b + lin_W[128+cls]) ----------------
__global__ __launch_bounds__(256) void k_embed(
    const float* __restrict__ x, const float* __restrict__ lin_W,
    const float* __restrict__ lin_b, const int* __restrict__ batch,
    const int* __restrict__ y, float* __restrict__ h, int M) {
  __shared__ float Al[32 * 128];
  __shared__ float Wl[32 * 128];
  int t = threadIdx.x;
  int row0 = blockIdx.x * 32;
  for (int i = t * 4; i < 32 * 128; i += 1024) {
    int r = i >> 7, k = i & 127;
    int gr = row0 + r;
    float4 v = {0.f, 0.f, 0.f, 0.f};
    if (gr < M) v = *(const float4*)&x[(size_t)gr * 128 + k];
    *(float4*)&Al[i] = v;
  }
  int c4 = (t & 31) * 4;
  int rb = (t >> 5) * 4;
  float acc[4][4] = {};
  for (int ks = 0; ks < 128; ks += 32) {
    __syncthreads();
    for (int i = t * 4; i < 32 * 128; i += 1024)
      *(float4*)&Wl[i] = *(const float4*)&lin_W[(size_t)ks * 128 + i];
    __syncthreads();
    for (int k = 0; k < 32; k += 4) {
      float4 a[4];
      #pragma unroll
      for (int r = 0; r < 4; ++r) a[r] = *(float4*)&Al[(rb + r) * 128 + ks + k];
      #pragma unroll
      for (int kk = 0; kk < 4; ++kk) {
        float4 w = *(float4*)&Wl[(k + kk) * 128 + c4];
        #pragma unroll
        for (int r = 0; r < 4; ++r) {
          float av = kk == 0 ? a[r].x : kk == 1 ? a[r].y : kk == 2 ? a[r].z : a[r].w;
          acc[r][0] = fmaf(av, w.x, acc[r][0]);
          acc[r][1] = fmaf(av, w.y, acc[r][1]);
          acc[r][2] = fmaf(av, w.z, acc[r][2]);
          acc[r][3] = fmaf(av, w.w, acc[r][3]);
        }
      }
    }
  }
  #pragma unroll
  for (int r = 0; r < 4; ++r) {
    int gr = row0 + rb + r;
    if (gr < M) {
      int cls = y[batch[gr]];
      const float* wrow = &lin_W[(size_t)(128 + cls) * 128];
      float4 o;
      o.x = leaky_f(acc[r][0] + lin_b[c4 + 0] + wrow[c4 + 0]);
      o.y = leaky_f(acc[r][1] + lin_b[c4 + 1] + wrow[c4 + 1]);
      o.z = leaky_f(acc[r][2] + lin_b[c4 + 2] + wrow[c4 + 2]);
      o.w = leaky_f(acc[r][3] + lin_b[c4 + 3] + wrow[c4 + 3]);
      *(float4*)&h[(size_t)gr * 128 + c4] = o;
    }
  }
}

// ---------------- per-conv node projections ----------------
// P layout per node (512 floats), R8 interleave:
//   [  0..127] Af
//   [128..255] As
//   [256..511] Bint: per channel-pair p (0..63): {Bf[2p], Bf[2p+1], Bs[2p], Bs[2p+1]}
// so k_agg's per-edge gather is ONE coalesced float4/lane (1KB contiguous).
__global__ __launch_bounds__(256) void k_proj(
    const float* __restrict__ h, const float* __restrict__ Wf,
    const float* __restrict__ Ws, float* __restrict__ P, int M) {
  __shared__ float Al[32 * 128];
  __shared__ float Wl[32 * 128];
  int t = threadIdx.x;
  int part = blockIdx.y;  // 0:Af 1:Bf 2:As 3:Bs
  const float* Wsrc = (part < 2 ? Wf : Ws) + (size_t)(part & 1) * (128 * 128);
  int row0 = blockIdx.x * 32;
  for (int i = t * 4; i < 32 * 128; i += 1024) {
    int r = i >> 7, k = i & 127;
    int gr = row0 + r;
    float4 v = {0.f, 0.f, 0.f, 0.f};
    if (gr < M) v = *(const float4*)&h[(size_t)gr * 128 + k];
    *(float4*)&Al[i] = v;
  }
  int c4 = (t & 31) * 4;
  int rb = (t >> 5) * 4;
  float acc[4][4] = {};
  for (int ks = 0; ks < 128; ks += 32) {
    __syncthreads();
    for (int i = t * 4; i < 32 * 128; i += 1024)
      *(float4*)&Wl[i] = *(const float4*)&Wsrc[(size_t)ks * 128 + i];
    __syncthreads();
    for (int k = 0; k < 32; k += 4) {
      float4 a[4];
      #pragma unroll
      for (int r = 0; r < 4; ++r) a[r] = *(float4*)&Al[(rb + r) * 128 + ks + k];
      #pragma unroll
      for (int kk = 0; kk < 4; ++kk) {
        float4 w = *(float4*)&Wl[(k + kk) * 128 + c4];
        #pragma unroll
        for (int r = 0; r < 4; ++r) {
          float av = kk == 0 ? a[r].x : kk == 1 ? a[r].y : kk == 2 ? a[r].z : a[r].w;
          acc[r][0] = fmaf(av, w.x, acc[r][0]);
          acc[r][1] = fmaf(av, w.y, acc[r][1]);
          acc[r][2] = fmaf(av, w.z, acc[r][2]);
          acc[r][3] = fmaf(av, w.w, acc[r][3]);
        }
      }
    }
  }
  #pragma unroll
  for (int r = 0; r < 4; ++r) {
    int gr = row0 + rb + r;
    if (gr < M) {
      float* Pn = P + (size_t)gr * 512;
      if (part == 0) {
        float4 o = {acc[r][0], acc[r][1], acc[r][2], acc[r][3]};
        *(float4*)&Pn[c4] = o;
      } else if (part == 2) {
        float4 o = {acc[r][0], acc[r][1], acc[r][2], acc[r][3]};
        *(float4*)&Pn[128 + c4] = o;
      } else {
        int pbase = 256 + (c4 >> 1) * 4 + (part == 3 ? 2 : 0);
        f32x2 lo = {acc[r][0], acc[r][1]};
        f32x2 hi = {acc[r][2], acc[r][3]};
        *(f32x2*)&Pn[pbase] = lo;
        *(f32x2*)&Pn[pbase + 4] = hi;
      }
    }
  }
}

// ---------------- fused aggregation (pull, CSR) ----------------
// R8: gather-path fix. R7 proved weights were never the stall (LDS weights,
// zero change). FETCH_SIZE accounting: 521 MB fetched vs ~230 MB unique —
// ~290 MB is P re-fetched from HBM because the ea_csr/h streams thrash P out
// of L3 (P 102MB + streams ~= L3 capacity). Changes:
//  1. interleaved Bint layout: per-edge gather = ONE float4/lane, 1KB
//     contiguous (was 2 x 512B) — halves gather transactions.
//  2. nontemporal loads for ea_csr/hin, nt store for hout: streams bypass
//     cache retention so P stays L3-resident.
//  3. 2-deep software prefetch of next edge's B-vector + 4x16 split FMA
//     chains: more latency overlap per wave.
__global__ __launch_bounds__(256)
void k_agg(
    const float* __restrict__ hin, const float* __restrict__ P,
    const int* __restrict__ off,
    const int* __restrict__ esrcArr, const float* __restrict__ ea_csr,
    const float* __restrict__ Wf, const float* __restrict__ Ws,
    const float* __restrict__ bfv, const float* __restrict__ bsv,
    float* __restrict__ hout, int N, int do_leaky) {
  __shared__ float WlF[32 * 128];
  __shared__ float WlS[32 * 128];
  int t = threadIdx.x;
  // stage edge-part weight rows (256..287) into LDS, coalesced float4
  for (int i = t * 4; i < 32 * 128; i += 1024) {
    *(float4*)&WlF[i] = *(const float4*)&Wf[(size_t)256 * 128 + i];
    *(float4*)&WlS[i] = *(const float4*)&Ws[(size_t)256 * 128 + i];
  }
  __syncthreads();
  int lane = t & 63;
  int wave = __builtin_amdgcn_readfirstlane(t >> 6);
  int gw = blockIdx.x * 4 + wave;
  int c2 = lane * 2;  // this lane owns channels c2, c2+1
  f32x2 bf2 = *(const f32x2*)&bfv[c2];
  f32x2 bs2 = *(const f32x2*)&bsv[c2];
  int nstreams = gridDim.x * 4;
  for (int n = gw; n < N; n += nstreams) {
    int i0 = __builtin_amdgcn_readfirstlane(off[n]);
    int i1 = __builtin_amdgcn_readfirstlane(off[n + 1]);
    f32x2 acc = __builtin_nontemporal_load((const f32x2*)&hin[(size_t)n * 128 + c2]);
    f32x2 gf0 = *(const f32x2*)&P[(size_t)n * 512 + c2] + bf2;        // Af + bf
    f32x2 gs0 = *(const f32x2*)&P[(size_t)n * 512 + 128 + c2] + bs2;  // As + bs
    if (i0 < i1) {
      int sP = __builtin_amdgcn_readfirstlane(esrcArr[i0]);
      f32x4 bP = *(const f32x4*)&P[(size_t)sP * 512 + 256 + lane * 4];
      #pragma unroll 1
      for (int i = i0; i < i1; ++i) {
        f32x4 b = bP;
        // prefetch next edge's B-vector (clamped; duplicate load on last iter)
        int inx = i + 1 < i1 ? i + 1 : i;
        int sN = __builtin_amdgcn_readfirstlane(esrcArr[inx]);
        bP = *(const f32x4*)&P[(size_t)sN * 512 + 256 + lane * 4];
        f32x2 gfA = gf0 + (f32x2){b.x, b.y};
        f32x2 gsA = gs0 + (f32x2){b.z, b.w};
        f32x2 gfB = {0.f, 0.f};
        f32x2 gsB = {0.f, 0.f};
        const float* e0 = ea_csr + (size_t)i * DK;
        #pragma unroll
        for (int q = 0; q < 4; ++q) {
          f32x4 a = __builtin_nontemporal_load((const f32x4*)&e0[q * 8]);
          f32x4 c = __builtin_nontemporal_load((const f32x4*)&e0[q * 8 + 4]);
          float ekk[8] = {a.x, a.y, a.z, a.w, c.x, c.y, c.z, c.w};
          #pragma unroll
          for (int j = 0; j < 8; ++j) {
            int k = q * 8 + j;
            f32x2 wfk = *(const f32x2*)&WlF[k * 128 + c2];  // LDS, shared
            f32x2 wsk = *(const f32x2*)&WlS[k * 128 + c2];
            f32x2 e2 = {ekk[j], ekk[j]};
            if (q < 2) { gfA += e2 * wfk; gsA += e2 * wsk; }
            else       { gfB += e2 * wfk; gsB += e2 * wsk; }
          }
        }
        acc += gate2(gfA + gfB, gsA + gsB);
      }
    }
    if (do_leaky) { acc.x = leaky_f(acc.x); acc.y = leaky_f(acc.y); }
    __builtin_nontemporal_store(acc, (f32x2*)&hout[(size_t)n * 128 + c2]);
  }
}

// ---------------- per-graph mean pool: partial sums over (G, S) grid ----------------
__device__ __forceinline__ int lbound(const int* a, int n, int key) {
  int lo = 0, hi = n;
  while (lo < hi) { int m = (lo + hi) >> 1; if (a[m] < key) lo = m + 1; else hi = m; }
  return lo;
}

__global__ void k_pool(const float* __restrict__ h, const int* __restrict__ batch,
                       float* __restrict__ pooled, int* __restrict__ gcnt, int N) {
  int g = blockIdx.x;
  int sidx = blockIdx.y, sgrid = gridDim.y;
  int t = threadIdx.x;  // 128 threads = channels
  int lo = lbound(batch, N, g);
  int hi = lbound(batch, N, g + 1);
  int len = hi - lo;
  if (sidx == 0 && t == 0) gcnt[g] = len;
  int per = (len + sgrid - 1) / sgrid;
  int a = lo + sidx * per;
  int b = min(hi, a + per);
  if (a >= b) return;
  float s = 0.f;
  for (int n = a; n < b; ++n) s += h[(size_t)n * 128 + t];
  atomicAdd(&pooled[g * 128 + t], s);
}

// ---------------- head: one-hot folded in as fc1_W row (128 + y[g]) ----------------
__global__ void k_fc(const float* __restrict__ pooled, const int* __restrict__ gcnt,
                     const int* __restrict__ y,
                     const float* __restrict__ W1, const float* __restrict__ b1,
                     const float* __restrict__ W2, const float* __restrict__ b2,
                     float* __restrict__ out) {
  int g = blockIdx.x;
  int j = threadIdx.x;  // 64 threads, only 0..31 compute
  float v = 0.f;
  if (j < 32) {
    int cnt = gcnt[g];
    float dot = 0.f;
    for (int k = 0; k < 128; ++k) dot = fmaf(pooled[g * 128 + k], W1[k * 32 + j], dot);
    float a = b1[j] + (cnt > 0 ? dot / (float)cnt + W1[(128 + y[g]) * 32 + j] : 0.f);
    a = leaky_f(a);
    v = a * W2[j];
  }
  #pragma unroll
  for (int o = 32; o > 0; o >>= 1) v += __shfl_down(v, o);
  if (j == 0) out[g] = 1.f / (1.f + __expf(-(v + b2[0])));
}

extern "C" void kernel_launch(void* const* d_in, const int* in_sizes, int n_in,
                              void* d_out, int out_size, void* d_ws, size_t ws_size,
                              hipStream_t stream) {
  const float* x        = (const float*)d_in[0];
  const int*   y        = (const int*)d_in[1];
  const int*   eidx     = (const int*)d_in[2];
  const float* ea       = (const float*)d_in[3];
  const int*   batch    = (const int*)d_in[4];
  const float* lin_W    = (const float*)d_in[5];
  const float* lin_b    = (const float*)d_in[6];
  const float* c1_Wf    = (const float*)d_in[7];
  const float* c1_bf    = (const float*)d_in[8];
  const float* c1_Ws    = (const float*)d_in[9];
  const float* c1_bs    = (const float*)d_in[10];
  const float* c2_Wf    = (const float*)d_in[11];
  const float* c2_bf    = (const float*)d_in[12];
  const float* c2_Ws    = (const float*)d_in[13];
  const float* c2_bs    = (const float*)d_in[14];
  const float* fc1_W    = (const float*)d_in[15];
  const float* fc1_b    = (const float*)d_in[16];
  const float* fc2_W    = (const float*)d_in[17];
  const float* fc2_b    = (const float*)d_in[18];
  float* out = (float*)d_out;

  const int N = in_sizes[0] / 128;
  const int G = in_sizes[1];
  const int E = in_sizes[2] / 2;
  const int* src = eidx;
  const int* dst = eidx + E;

  // workspace layout (16B aligned chunks)
  char* w = (char*)d_ws;
  float* P  = (float*)w;  w += (size_t)N * 512 * 4;
  float* hA = (float*)w;  w += (size_t)N * 128 * 4;
  float* hB = (float*)w;  w += (size_t)N * 128 * 4;
  float* pooled = (float*)w; w += (size_t)G * 128 * 4;
  int* gcnt = (int*)w; w += ((size_t)G * 4 + 15) & ~(size_t)15;
  int* cnt = (int*)w; w += (size_t)N * 4;
  int* off = (int*)w; w += ((size_t)(N + 1) * 4 + 15) & ~(size_t)15;
  int* eid = (int*)w; w += (size_t)E * 4;
  int* esrc = (int*)w; w += (size_t)E * 4;
  float* ea_csr = (float*)w; w += (size_t)E * DK * 4;

  // CSR build
  hipMemsetAsync(cnt, 0, (size_t)N * 4, stream);
  hipMemsetAsync(pooled, 0, (size_t)G * 128 * 4, stream);
  k_hist<<<(E + 255) / 256, 256, 0, stream>>>(dst, cnt, E);
  k_scan<<<1, 1024, 0, stream>>>(cnt, off, cnt /*reuse as cursor*/, N);
  k_fill<<<(E + 255) / 256, 256, 0, stream>>>(dst, src, cnt, eid, esrc, E);
  k_gea<<<(E * 8 + 255) / 256, 256, 0, stream>>>(eid, ea, ea_csr, E);

  // embed
  k_embed<<<(N + 31) / 32, 256, 0, stream>>>(x, lin_W, lin_b, batch, y, hA, N);

  // conv1
  k_proj<<<dim3((N + 31) / 32, 4), 256, 0, stream>>>(hA, c1_Wf, c1_Ws, P, N);
  k_agg<<<2048, 256, 0, stream>>>(hA, P, off, esrc, ea_csr, c1_Wf, c1_Ws, c1_bf, c1_bs, hB, N, 1);

  // conv2
  k_proj<<<dim3((N + 31) / 32, 4), 256, 0, stream>>>(hB, c2_Wf, c2_Ws, P, N);
  k_agg<<<2048, 256, 0, stream>>>(hB, P, off, esrc, ea_csr, c2_Wf, c2_Ws, c2_bf, c2_bs, hA, N, 0);

  // pool + head
  k_pool<<<dim3(G, 8), 128, 0, stream>>>(hA, batch, pooled, gcnt, N);
  k_fc<<<G, 64, 0, stream>>>(pooled, gcnt, y, fc1_W, fc1_b, fc2_W, fc2_b, out);
}